// Round 9
// baseline (636.907 us; speedup 1.0000x reference)
//
#include <hip/hip_runtime.h>

#define NN 100000
#define EE 1600000
#define DD 64
#define CC 10
#define GG 512
#define LL 5
#define NPAD 100352            // 392*256
#define N64 (NN * DD)
#define NB 392                 // coarse buckets (256 nodes each)
#define PCH 4096               // edges per partition block
#define BCAP 6144              // per-bucket LDS capacity (mean 4082, >30 sigma)
#define SC 8                   // BN stats shadow copies
#define PREPG 1563             // (NN+63)/64

typedef short bf16x8 __attribute__((ext_vector_type(8)));
typedef float f32x4  __attribute__((ext_vector_type(4)));
union U16 { uint4 u; bf16x8 h; };

__device__ __forceinline__ float bits2f(unsigned int b) { return __uint_as_float(b); }
__device__ __forceinline__ float bf2f(unsigned short s) { return __uint_as_float((unsigned int)s << 16); }
__device__ __forceinline__ unsigned short f2bf_rne(float v) {
    unsigned int b = __float_as_uint(v);
    return (unsigned short)((b + 0x7fffu + ((b >> 16) & 1u)) >> 16);
}
__device__ __forceinline__ void unpack8(uint4 u, float* f) {
    f[0] = bits2f(u.x << 16); f[1] = bits2f(u.x & 0xffff0000u);
    f[2] = bits2f(u.y << 16); f[3] = bits2f(u.y & 0xffff0000u);
    f[4] = bits2f(u.z << 16); f[5] = bits2f(u.z & 0xffff0000u);
    f[6] = bits2f(u.w << 16); f[7] = bits2f(u.w & 0xffff0000u);
}
__device__ __forceinline__ uint4 pack8(const float* f) {
    uint4 u;
    u.x = (unsigned int)f2bf_rne(f[0]) | ((unsigned int)f2bf_rne(f[1]) << 16);
    u.y = (unsigned int)f2bf_rne(f[2]) | ((unsigned int)f2bf_rne(f[3]) << 16);
    u.z = (unsigned int)f2bf_rne(f[4]) | ((unsigned int)f2bf_rne(f[5]) << 16);
    u.w = (unsigned int)f2bf_rne(f[6]) | ((unsigned int)f2bf_rne(f[7]) << 16);
    return u;
}
__device__ __forceinline__ void acc8(uint4 u, float* a) {
    float t[8];
    unpack8(u, t);
    #pragma unroll
    for (int k = 0; k < 8; ++k) a[k] += t[k];
}

// async global -> LDS, 16B per lane (dest = lds_base + lane*16, src per-lane)
__device__ __forceinline__ void glds16(const void* g, void* l) {
    __builtin_amdgcn_global_load_lds(
        (const __attribute__((address_space(1))) void*)g,
        (__attribute__((address_space(3))) void*)l, 16, 0, 0);
}

// ======== fused prep: x->bf16 + layer-0 pool | W transpose | edge hist ========
__global__ __launch_bounds__(256) void prep_all_k(
    const float* __restrict__ x, const int* __restrict__ batch,
    unsigned short* __restrict__ hbuf, float* __restrict__ pooled,
    const float* __restrict__ W1, const float* __restrict__ W2,
    unsigned short* __restrict__ wt,
    const int* __restrict__ ei, int* __restrict__ bh)
{
    __shared__ int cnt[NB];
    const int bid = blockIdx.x;
    const int t = threadIdx.x;
    if (bid < PREPG) {
        int f = t & 63;
        int q = t >> 6;
        int n0 = bid * 64 + q * 16;
        int nmax = NN - n0; if (nmax > 16) nmax = 16;
        float acc = 0.f;
        int curg = -1;
        #pragma unroll 4
        for (int i = 0; i < nmax; ++i) {
            int n = n0 + i;
            int g = batch[n];
            if (g != curg) {
                if (curg >= 0) atomicAdd(&pooled[(size_t)curg * DD + f], acc);
                acc = 0.f; curg = g;
            }
            float v = x[(size_t)n * DD + f];
            hbuf[(size_t)n * DD + f] = f2bf_rne(v);
            acc += v;
        }
        if (curg >= 0) atomicAdd(&pooled[(size_t)curg * DD + f], acc);
    } else if (bid < PREPG + 8) {
        int mat = bid - PREPG;
        const float* src = (mat < 4) ? (W1 + (size_t)mat * 4096)
                                     : (W2 + (size_t)(mat - 4) * 4096);
        for (int idx = t; idx < 4096; idx += 256) {
            int c = idx >> 6, k = idx & 63;
            wt[(size_t)mat * 4096 + c * 64 + k] = f2bf_rne(src[k * 64 + c]);
        }
    } else {
        int hid = bid - PREPG - 8;          // 0..511
        for (int i = t; i < NB; i += 256) cnt[i] = 0;
        __syncthreads();
        for (int e = hid * 256 + t; e < EE; e += 512 * 256)
            atomicAdd(&cnt[ei[EE + e] >> 8], 1);
        __syncthreads();
        for (int i = t; i < NB; i += 256)
            if (cnt[i]) atomicAdd(&bh[i], cnt[i]);
    }
}

// ================= coarse scan =================
__global__ __launch_bounds__(512) void bscan_k(const int* __restrict__ bh,
                                               int* __restrict__ bo,
                                               int* __restrict__ bcur) {
    __shared__ int s[512];
    int t = threadIdx.x;
    int v = (t < NB) ? bh[t] : 0;
    s[t] = v;
    __syncthreads();
    for (int d = 1; d < 512; d <<= 1) {
        int a = (t >= d) ? s[t - d] : 0;
        __syncthreads();
        s[t] += a;
        __syncthreads();
    }
    int excl = s[t] - v;
    if (t < NB) { bo[t] = excl; bcur[t] = excl; }
    if (t == NB - 1) bo[NB] = excl + v;
}

// ============ partition edges into bucket-contiguous staging ============
// stage entry: src (bits 0..16) | dst-local-in-bucket (bits 17..24)
__global__ __launch_bounds__(256) void partition_k(const int* __restrict__ ei,
                                                   int* __restrict__ bcur,
                                                   unsigned int* __restrict__ stage) {
    __shared__ int hist[NB];
    __shared__ int base[NB];
    __shared__ int gbase[NB];
    __shared__ int cnt2[NB];
    __shared__ int scanbuf[512];
    __shared__ unsigned int pairs[PCH];
    __shared__ unsigned short pbkt[PCH];
    int t = threadIdx.x;
    int e0 = blockIdx.x * PCH;
    int nE = EE - e0; if (nE > PCH) nE = PCH;

    for (int i = t; i < NB; i += 256) { hist[i] = 0; cnt2[i] = 0; }
    __syncthreads();

    int mys[16], myd[16];
    #pragma unroll
    for (int i = 0; i < 16; ++i) {
        int idx = i * 256 + t;
        if (idx < nE) {
            mys[i] = ei[e0 + idx];
            myd[i] = ei[EE + e0 + idx];
            atomicAdd(&hist[myd[i] >> 8], 1);
        } else myd[i] = -1;
    }
    __syncthreads();

    scanbuf[t]       = (t < NB) ? hist[t] : 0;
    scanbuf[t + 256] = (t + 256 < NB) ? hist[t + 256] : 0;
    __syncthreads();
    for (int d = 1; d < 512; d <<= 1) {
        int a0 = (t >= d) ? scanbuf[t - d] : 0;
        int a1 = ((t + 256) >= d) ? scanbuf[t + 256 - d] : 0;
        __syncthreads();
        scanbuf[t] += a0;
        scanbuf[t + 256] += a1;
        __syncthreads();
    }
    if (t < NB)       base[t]       = scanbuf[t] - hist[t];
    if (t + 256 < NB) base[t + 256] = scanbuf[t + 256] - hist[t + 256];
    __syncthreads();

    #pragma unroll
    for (int i = 0; i < 16; ++i) {
        if (myd[i] >= 0) {
            int b = myd[i] >> 8;
            int p = base[b] + atomicAdd(&cnt2[b], 1);
            pairs[p] = (unsigned)mys[i] | ((unsigned)(myd[i] & 255) << 17);
            pbkt[p] = (unsigned short)b;
        }
    }
    __syncthreads();
    for (int i = t; i < NB; i += 256)
        if (hist[i]) gbase[i] = atomicAdd(&bcur[i], hist[i]);
    __syncthreads();
    for (int p = t; p < nE; p += 256) {
        int b = pbkt[p];
        stage[gbase[b] + (p - base[b])] = pairs[p];
    }
}

// ============ per-bucket CSR: adj + offs, all in LDS ============
__global__ __launch_bounds__(256) void bucket_csr_k(const unsigned int* __restrict__ stage,
                                                    const int* __restrict__ bo,
                                                    int* __restrict__ adj,
                                                    int* __restrict__ offs) {
    __shared__ int deg[256];
    __shared__ int sb[256];
    __shared__ int nb_[256];
    __shared__ int c2[256];
    __shared__ int loc[BCAP];
    int b = blockIdx.x;
    int s0 = bo[b], s1 = bo[b + 1];
    int cnt = s1 - s0;
    int t = threadIdx.x;

    deg[t] = 0;
    __syncthreads();
    for (int i = t; i < cnt; i += 256) atomicAdd(&deg[(stage[s0 + i] >> 17) & 255], 1);
    __syncthreads();
    sb[t] = deg[t];
    __syncthreads();
    for (int d = 1; d < 256; d <<= 1) {
        int a = (t >= d) ? sb[t - d] : 0;
        __syncthreads();
        sb[t] += a;
        __syncthreads();
    }
    int nbase = sb[t] - deg[t];
    nb_[t] = nbase;
    c2[t] = 0;
    offs[b * 256 + t] = s0 + nbase;
    __syncthreads();

    if (cnt <= BCAP) {
        for (int i = t; i < cnt; i += 256) {
            unsigned int pr = stage[s0 + i];
            int ln = (pr >> 17) & 255;
            int p = nb_[ln] + atomicAdd(&c2[ln], 1);
            loc[p] = (int)(pr & 0x1FFFF);
        }
        __syncthreads();
        for (int i = t; i < cnt; i += 256) adj[s0 + i] = loc[i];
    } else {            // statistically unreachable fallback
        for (int i = t; i < cnt; i += 256) {
            unsigned int pr = stage[s0 + i];
            int ln = (pr >> 17) & 255;
            int p = nb_[ln] + atomicAdd(&c2[ln], 1);
            adj[s0 + p] = (int)(pr & 0x1FFFF);
        }
    }
}

// ========== K1 v8: global_load_lds deep-pipelined gather -> MFMA GEMM1 + stats1 ==========
// R8 post-mortem: VGPR=24 twice -- any reg-staged pipeline gets collapsed by
// the allocator to ~2 loads in flight (Little's law caps scattered BW ~3.1TB/s).
// v8 stages rows via global_load_lds (no dest VGPRs -> depth is ours):
//  - per wave-round: 2 glds = 16 rows (2KB) into per-wave LDS double-buffer
//  - adj prefetched TWO rounds ahead (compiler's auto-wait for addr = vmcnt(4))
//  - manual counted s_waitcnt vmcnt(4) (never 0) + sched_barrier fences (rule 18)
//  - uniform instr stream: clamped adj[end-1] idx (L2-hot), predicated acc
//  - lane reads back its own 16B slot; strict edge order -> bit-identical sums
// LDS 40KB (32 stage + 8 aLDS) -> 4 blocks/CU, 32 waves.
__global__ __launch_bounds__(512, 8) void layer1_k(
    const unsigned short* __restrict__ hb, const int* __restrict__ adj,
    const int* __restrict__ offs, const float* __restrict__ epsArr, int l,
    const unsigned short* __restrict__ wtm, const float* __restrict__ bias,
    unsigned short* __restrict__ z1, float* __restrict__ stats1,
    float* __restrict__ stats2z)
{
    __shared__ unsigned short aLDS[64 * 64];     // 8KB, XOR-swizzled 16B units
    __shared__ uint4 stage4[8][2][2][64];        // 32KB: wave x buf x edge x lane
    const int t = threadIdx.x;
    const int lane = t & 63;
    const int w = t >> 6;          // 0..7
    const int n15 = lane & 15;
    const int quad = lane >> 4;

    if (blockIdx.x < SC && t < 128) stats2z[blockIdx.x * 128 + t] = 0.f;

    const float epsv = 1.0f + epsArr[l];
    const int c8 = lane & 7;
    const int g8 = lane >> 3;
    // ---- gather: one row per 8-lane group; rows staged via glds pipeline ----
    {
        int lr = w * 8 + g8;
        int n = blockIdx.x * 64 + lr;
        float acc[8] = {0.f,0.f,0.f,0.f,0.f,0.f,0.f,0.f};
        int jbeg = 0, end = 0;
        if (n < NN) {
            uint4 a = *(const uint4*)(hb + (size_t)n * DD + c8 * 8);
            unpack8(a, acc);
            #pragma unroll
            for (int k = 0; k < 8; ++k) acc[k] *= epsv;
            jbeg = offs[n]; end = offs[n + 1];
        }
        int jcur = jbeg;
        // clamped adj index: inactive -> last real edge (L2-hot) or 0
        auto idxf = [&](int jj) { return jj < end ? jj : (end > jbeg ? end - 1 : 0); };

        // prologue: adj rounds 0,1 then glds round 0
        int a0 = adj[idxf(jcur)];
        int a1 = adj[idxf(jcur + 1)];
        int b0 = adj[idxf(jcur + 2)];
        int b1 = adj[idxf(jcur + 3)];
        __builtin_amdgcn_sched_barrier(0);
        glds16(hb + (size_t)a0 * DD + c8 * 8, &stage4[w][0][0][0]);
        glds16(hb + (size_t)a1 * DD + c8 * 8, &stage4[w][0][1][0]);

        int r = 0;
        while (__any(jcur < end)) {
            __builtin_amdgcn_sched_barrier(0);
            // adj for round r+2
            int c0 = adj[idxf(jcur + 4)];
            int c1 = adj[idxf(jcur + 5)];
            __builtin_amdgcn_sched_barrier(0);
            // glds round r+1 (uses b regs loaded 1 iter ago -> auto-wait vmcnt(4))
            int pn = (r + 1) & 1;
            glds16(hb + (size_t)b0 * DD + c8 * 8, &stage4[w][pn][0][0]);
            glds16(hb + (size_t)b1 * DD + c8 * 8, &stage4[w][pn][1][0]);
            // retire round r (2 glds oldest of 6 outstanding) -- counted, never 0
            asm volatile("s_waitcnt vmcnt(4)" ::: "memory");
            __builtin_amdgcn_sched_barrier(0);
            // accumulate round r (strict edge order, predicated)
            int pc = r & 1;
            if (jcur < end)     acc8(stage4[w][pc][0][lane], acc);
            if (jcur + 1 < end) acc8(stage4[w][pc][1][lane], acc);
            b0 = c0; b1 = c1;
            jcur += 2; ++r;
        }
        int pu = c8 ^ (lr & 7);
        *(uint4*)(aLDS + lr * 64 + pu * 8) = pack8(acc);
    }

    // ---- B fragments for this wave's 2 column tiles (issued before barrier) ----
    const int rt = w & 3;          // row tile (16 rows)
    const int cb = (w >> 2) * 2;   // first of 2 column tiles
    U16 bfr[2][2];
    #pragma unroll
    for (int ci = 0; ci < 2; ++ci)
        #pragma unroll
        for (int ks = 0; ks < 2; ++ks)
            bfr[ci][ks].u = *(const uint4*)(wtm + (size_t)((cb + ci) * 16 + n15) * 64 + ks * 32 + quad * 8);

    __syncthreads();               // A-rows in LDS are cross-wave

    // ---- A fragments from LDS (swizzled) ----
    U16 afr[2];
    int lr2 = rt * 16 + n15;
    #pragma unroll
    for (int ks = 0; ks < 2; ++ks) {
        int pu = (ks * 4 + quad) ^ (lr2 & 7);
        afr[ks].u = *(const uint4*)(aLDS + lr2 * 64 + pu * 8);
    }

    const int rowg0 = blockIdx.x * 64 + rt * 16;
    const int copy = blockIdx.x & (SC - 1);
    #pragma unroll
    for (int ci = 0; ci < 2; ++ci) {
        int ct = cb + ci;
        f32x4 acc = {0.f, 0.f, 0.f, 0.f};
        acc = __builtin_amdgcn_mfma_f32_16x16x32_bf16(afr[0].h, bfr[ci][0].h, acc, 0, 0, 0);
        acc = __builtin_amdgcn_mfma_f32_16x16x32_bf16(afr[1].h, bfr[ci][1].h, acc, 0, 0, 0);
        int col = ct * 16 + n15;
        float bcol = bias[col];
        float s = 0.f, ss = 0.f;
        #pragma unroll
        for (int r = 0; r < 4; ++r) {
            int rg = rowg0 + quad * 4 + r;
            float v = acc[r] + bcol;
            if (rg < NN) {
                z1[(size_t)rg * DD + col] = f2bf_rne(v);
                s += v;
                ss = fmaf(v, v, ss);
            }
        }
        s  += __shfl_xor(s, 16, 64);  s  += __shfl_xor(s, 32, 64);
        ss += __shfl_xor(ss, 16, 64); ss += __shfl_xor(ss, 32, 64);
        if (lane < 16) {
            atomicAdd(&stats1[copy * 128 + ct * 16 + lane], s);
            atomicAdd(&stats1[copy * 128 + 64 + ct * 16 + lane], ss);
        }
    }
}

// ========== K2: inline BN1 + MFMA GEMM2 + stats2 ==========
__global__ __launch_bounds__(256) void layer2_k(
    const unsigned short* __restrict__ z1, const float* __restrict__ stats1,
    const float* __restrict__ gamma, const float* __restrict__ beta, int off,
    const unsigned short* __restrict__ wtm, const float* __restrict__ bias,
    unsigned short* __restrict__ z2, float* __restrict__ stats2)
{
    __shared__ float ssS[128];
    const int t = threadIdx.x;
    const int lane = t & 63;
    const int w = t >> 6;
    const int n15 = lane & 15;
    const int quad = lane >> 4;
    const int rowg0 = blockIdx.x * 64 + w * 16;

    // ---- issue independent global loads BEFORE the stats barrier ----
    U16 bfr[4][2];
    #pragma unroll
    for (int ct = 0; ct < 4; ++ct)
        #pragma unroll
        for (int ks = 0; ks < 2; ++ks)
            bfr[ct][ks].u = *(const uint4*)(wtm + (size_t)(ct * 16 + n15) * 64 + ks * 32 + quad * 8);

    int arow = rowg0 + n15;
    int arowc = (arow < NN) ? arow : (NN - 1);
    uint4 raw[2];
    #pragma unroll
    for (int ks = 0; ks < 2; ++ks)
        raw[ks] = *(const uint4*)(z1 + (size_t)arowc * DD + ks * 32 + quad * 8);

    if (t < 64) {
        float S = 0.f, SS = 0.f;
        #pragma unroll
        for (int c = 0; c < SC; ++c) { S += stats1[c * 128 + t]; SS += stats1[c * 128 + 64 + t]; }
        float inv_n = 1.0f / (float)NN;
        float mean = S * inv_n;
        float var  = SS * inv_n - mean * mean;
        float sc = gamma[off + t] * rsqrtf(var + 1e-5f);
        ssS[t] = sc;
        ssS[64 + t] = beta[off + t] - sc * mean;
    }
    __syncthreads();

    U16 afr[2];
    #pragma unroll
    for (int ks = 0; ks < 2; ++ks) {
        float f[8];
        unpack8(raw[ks], f);
        int k0 = ks * 32 + quad * 8;
        #pragma unroll
        for (int j = 0; j < 8; ++j)
            f[j] = fmaxf(fmaf(ssS[k0 + j], f[j], ssS[64 + k0 + j]), 0.f);
        afr[ks].u = pack8(f);
    }

    const int copy = blockIdx.x & (SC - 1);
    #pragma unroll
    for (int ct = 0; ct < 4; ++ct) {
        f32x4 acc = {0.f, 0.f, 0.f, 0.f};
        acc = __builtin_amdgcn_mfma_f32_16x16x32_bf16(afr[0].h, bfr[ct][0].h, acc, 0, 0, 0);
        acc = __builtin_amdgcn_mfma_f32_16x16x32_bf16(afr[1].h, bfr[ct][1].h, acc, 0, 0, 0);
        int col = ct * 16 + n15;
        float bcol = bias[col];
        float s = 0.f, ss = 0.f;
        #pragma unroll
        for (int r = 0; r < 4; ++r) {
            int rg = rowg0 + quad * 4 + r;
            float v = acc[r] + bcol;
            if (rg < NN) {
                z2[(size_t)rg * DD + col] = f2bf_rne(v);
                s += v;
                ss = fmaf(v, v, ss);
            }
        }
        s  += __shfl_xor(s, 16, 64);  s  += __shfl_xor(s, 32, 64);
        ss += __shfl_xor(ss, 16, 64); ss += __shfl_xor(ss, 32, 64);
        if (lane < 16) {
            atomicAdd(&stats2[copy * 128 + ct * 16 + lane], s);
            atomicAdd(&stats2[copy * 128 + 64 + ct * 16 + lane], ss);
        }
    }
}

// ========== K3: inline BN2 + ReLU + hb write + segmented pool ==========
__global__ __launch_bounds__(256) void layer3_k(
    const unsigned short* __restrict__ z2, const float* __restrict__ stats2,
    const float* __restrict__ gamma, const float* __restrict__ beta, int off,
    const int* __restrict__ batch, unsigned short* __restrict__ hout,
    float* __restrict__ pooled, float* __restrict__ stats1z)
{
    __shared__ float ssS[128];
    int t = threadIdx.x;
    if (blockIdx.x < SC && t < 128) stats1z[blockIdx.x * 128 + t] = 0.f;
    if (t < 64) {
        float S = 0.f, SS = 0.f;
        #pragma unroll
        for (int c = 0; c < SC; ++c) { S += stats2[c * 128 + t]; SS += stats2[c * 128 + 64 + t]; }
        float inv_n = 1.0f / (float)NN;
        float mean = S * inv_n;
        float var  = SS * inv_n - mean * mean;
        float sc = gamma[off + t] * rsqrtf(var + 1e-5f);
        ssS[t] = sc;
        ssS[64 + t] = beta[off + t] - sc * mean;
    }
    __syncthreads();

    int f = t & 63;
    int q = t >> 6;
    int n0 = blockIdx.x * 64 + q * 16;
    int nmax = NN - n0; if (nmax > 16) nmax = 16;
    float sc = ssS[f], sh = ssS[64 + f];
    float acc = 0.f;
    int curg = -1;
    #pragma unroll 4
    for (int i = 0; i < nmax; ++i) {
        int n = n0 + i;
        int g = batch[n];
        if (g != curg) {
            if (curg >= 0) atomicAdd(&pooled[(size_t)curg * DD + f], acc);
            acc = 0.f; curg = g;
        }
        float v = bf2f(z2[(size_t)n * DD + f]);
        v = fmaxf(fmaf(sc, v, sh), 0.f);
        hout[(size_t)n * DD + f] = f2bf_rne(v);
        acc += v;
    }
    if (curg >= 0) atomicAdd(&pooled[(size_t)curg * DD + f], acc);
}

// ================= jumping-knowledge readout =================
__global__ void readout_k(const float* __restrict__ pooled,
                          const float* __restrict__ Wp, const float* __restrict__ bp,
                          float* __restrict__ out)
{
    int gc = blockIdx.x * blockDim.x + threadIdx.x;
    if (gc >= GG * CC) return;
    int g = gc / CC, c = gc - g * CC;
    float acc = 0.f;
    for (int l = 0; l < LL; ++l) {
        acc += bp[l * CC + c];
        const float* p  = pooled + ((size_t)l * GG + g) * DD;
        const float* wv = Wp + (size_t)l * DD * CC + c;
        #pragma unroll 8
        for (int f = 0; f < DD; ++f) acc = fmaf(p[f], wv[f * CC], acc);
    }
    out[gc] = acc;
}

extern "C" void kernel_launch(void* const* d_in, const int* in_sizes, int n_in,
                              void* d_out, int out_size, void* d_ws, size_t ws_size,
                              hipStream_t stream) {
    const float* x     = (const float*)d_in[0];
    const int*   ei    = (const int*)d_in[1];
    const int*   batch = (const int*)d_in[2];
    const float* eps   = (const float*)d_in[3];
    const float* W1    = (const float*)d_in[4];
    const float* b1    = (const float*)d_in[5];
    const float* g1    = (const float*)d_in[6];
    const float* be1   = (const float*)d_in[7];
    const float* W2    = (const float*)d_in[8];
    const float* b2    = (const float*)d_in[9];
    const float* gout  = (const float*)d_in[10];
    const float* beout = (const float*)d_in[11];
    const float* Wp    = (const float*)d_in[12];
    const float* bp    = (const float*)d_in[13];
    float* out = (float*)d_out;

    // ---- workspace layout (16B-aligned sections; bh adjacent to pooled so
    //      one memset covers bh+pooled+stats) ----
    unsigned int* stage = (unsigned int*)d_ws;          // EE*4
    int* adj   = (int*)(stage + EE);                    // EE*4
    int* offs  = adj + EE;                              // (NPAD+256)
    int* bo    = offs + NPAD + 256;                     // 400
    int* bcur  = bo + 400;                              // 400
    int* bh    = bcur + 400;                            // 400
    float* pooled = (float*)(bh + 400);                 // LL*GG*DD
    float* stats1 = pooled + (size_t)LL * GG * DD;      // SC*128
    float* stats2 = stats1 + SC * 128;                  // SC*128
    unsigned short* hb  = (unsigned short*)(stats2 + SC * 128);
    unsigned short* z1b = hb + N64;
    unsigned short* z2b = z1b + N64;
    unsigned short* wt  = z2b + N64;                    // 8*4096

    // ---- single memset: bh + pooled + stats1 + stats2 ----
    hipMemsetAsync(bh, 0, (400 + (size_t)LL * GG * DD + 2 * SC * 128) * sizeof(int), stream);
    // ---- fused prep (x->bf16 + pool0 | W^T | edge hist) ----
    prep_all_k<<<PREPG + 8 + 512, 256, 0, stream>>>(x, batch, hb, pooled, W1, W2, wt, ei, bh);
    bscan_k<<<1, 512, 0, stream>>>(bh, bo, bcur);
    partition_k<<<(EE + PCH - 1) / PCH, 256, 0, stream>>>(ei, bcur, stage);
    bucket_csr_k<<<NB, 256, 0, stream>>>(stage, bo, adj, offs);

    const int gemm_grid = (NN + 63) / 64;
    const int node_grid = (NN + 63) / 64;
    for (int l = 0; l < LL - 1; ++l) {
        layer1_k<<<gemm_grid, 512, 0, stream>>>(
            hb, adj, offs, eps, l, wt + (size_t)l * 4096, b1 + l * DD, z1b, stats1, stats2);
        layer2_k<<<gemm_grid, 256, 0, stream>>>(
            z1b, stats1, g1, be1, l * DD, wt + (size_t)(4 + l) * 4096, b2 + l * DD, z2b, stats2);
        layer3_k<<<node_grid, 256, 0, stream>>>(
            z2b, stats2, gout, beout, l * DD, batch, hb,
            pooled + (size_t)(l + 1) * GG * DD, stats1);
    }
    readout_k<<<(GG * CC + 255) / 256, 256, 0, stream>>>(pooled, Wp, bp, out);
}

// Round 10
// 616.585 us; speedup vs baseline: 1.0330x; 1.0330x over previous
//
#include <hip/hip_runtime.h>

#define NN 100000
#define EE 1600000
#define DD 64
#define CC 10
#define GG 512
#define LL 5
#define NPAD 100352            // 392*256
#define N64 (NN * DD)
#define NB 392                 // coarse buckets (256 nodes each)
#define PCH 4096               // edges per partition block
#define BCAP 6144              // per-bucket LDS capacity (mean 4082, >30 sigma)
#define SC 8                   // BN stats shadow copies
#define PREPG 1563             // (NN+63)/64

typedef short bf16x8 __attribute__((ext_vector_type(8)));
typedef float f32x4  __attribute__((ext_vector_type(4)));
union U16 { uint4 u; bf16x8 h; };

__device__ __forceinline__ float bits2f(unsigned int b) { return __uint_as_float(b); }
__device__ __forceinline__ float bf2f(unsigned short s) { return __uint_as_float((unsigned int)s << 16); }
__device__ __forceinline__ unsigned short f2bf_rne(float v) {
    unsigned int b = __float_as_uint(v);
    return (unsigned short)((b + 0x7fffu + ((b >> 16) & 1u)) >> 16);
}
__device__ __forceinline__ void unpack8(uint4 u, float* f) {
    f[0] = bits2f(u.x << 16); f[1] = bits2f(u.x & 0xffff0000u);
    f[2] = bits2f(u.y << 16); f[3] = bits2f(u.y & 0xffff0000u);
    f[4] = bits2f(u.z << 16); f[5] = bits2f(u.z & 0xffff0000u);
    f[6] = bits2f(u.w << 16); f[7] = bits2f(u.w & 0xffff0000u);
}
__device__ __forceinline__ uint4 pack8(const float* f) {
    uint4 u;
    u.x = (unsigned int)f2bf_rne(f[0]) | ((unsigned int)f2bf_rne(f[1]) << 16);
    u.y = (unsigned int)f2bf_rne(f[2]) | ((unsigned int)f2bf_rne(f[3]) << 16);
    u.z = (unsigned int)f2bf_rne(f[4]) | ((unsigned int)f2bf_rne(f[5]) << 16);
    u.w = (unsigned int)f2bf_rne(f[6]) | ((unsigned int)f2bf_rne(f[7]) << 16);
    return u;
}
__device__ __forceinline__ void acc8(uint4 u, float* a) {
    float t[8];
    unpack8(u, t);
    #pragma unroll
    for (int k = 0; k < 8; ++k) a[k] += t[k];
}

// ======== fused prep: x->bf16 + layer-0 pool | W transpose | edge hist ========
__global__ __launch_bounds__(256) void prep_all_k(
    const float* __restrict__ x, const int* __restrict__ batch,
    unsigned short* __restrict__ hbuf, float* __restrict__ pooled,
    const float* __restrict__ W1, const float* __restrict__ W2,
    unsigned short* __restrict__ wt,
    const int* __restrict__ ei, int* __restrict__ bh)
{
    __shared__ int cnt[NB];
    const int bid = blockIdx.x;
    const int t = threadIdx.x;
    if (bid < PREPG) {
        int f = t & 63;
        int q = t >> 6;
        int n0 = bid * 64 + q * 16;
        int nmax = NN - n0; if (nmax > 16) nmax = 16;
        float acc = 0.f;
        int curg = -1;
        #pragma unroll 4
        for (int i = 0; i < nmax; ++i) {
            int n = n0 + i;
            int g = batch[n];
            if (g != curg) {
                if (curg >= 0) atomicAdd(&pooled[(size_t)curg * DD + f], acc);
                acc = 0.f; curg = g;
            }
            float v = x[(size_t)n * DD + f];
            hbuf[(size_t)n * DD + f] = f2bf_rne(v);
            acc += v;
        }
        if (curg >= 0) atomicAdd(&pooled[(size_t)curg * DD + f], acc);
    } else if (bid < PREPG + 8) {
        int mat = bid - PREPG;
        const float* src = (mat < 4) ? (W1 + (size_t)mat * 4096)
                                     : (W2 + (size_t)(mat - 4) * 4096);
        for (int idx = t; idx < 4096; idx += 256) {
            int c = idx >> 6, k = idx & 63;
            wt[(size_t)mat * 4096 + c * 64 + k] = f2bf_rne(src[k * 64 + c]);
        }
    } else {
        int hid = bid - PREPG - 8;          // 0..511
        for (int i = t; i < NB; i += 256) cnt[i] = 0;
        __syncthreads();
        for (int e = hid * 256 + t; e < EE; e += 512 * 256)
            atomicAdd(&cnt[ei[EE + e] >> 8], 1);
        __syncthreads();
        for (int i = t; i < NB; i += 256)
            if (cnt[i]) atomicAdd(&bh[i], cnt[i]);
    }
}

// ================= coarse scan =================
__global__ __launch_bounds__(512) void bscan_k(const int* __restrict__ bh,
                                               int* __restrict__ bo,
                                               int* __restrict__ bcur) {
    __shared__ int s[512];
    int t = threadIdx.x;
    int v = (t < NB) ? bh[t] : 0;
    s[t] = v;
    __syncthreads();
    for (int d = 1; d < 512; d <<= 1) {
        int a = (t >= d) ? s[t - d] : 0;
        __syncthreads();
        s[t] += a;
        __syncthreads();
    }
    int excl = s[t] - v;
    if (t < NB) { bo[t] = excl; bcur[t] = excl; }
    if (t == NB - 1) bo[NB] = excl + v;
}

// ============ partition edges into bucket-contiguous staging ============
// stage entry: src (bits 0..16) | dst-local-in-bucket (bits 17..24)
__global__ __launch_bounds__(256) void partition_k(const int* __restrict__ ei,
                                                   int* __restrict__ bcur,
                                                   unsigned int* __restrict__ stage) {
    __shared__ int hist[NB];
    __shared__ int base[NB];
    __shared__ int gbase[NB];
    __shared__ int cnt2[NB];
    __shared__ int scanbuf[512];
    __shared__ unsigned int pairs[PCH];
    __shared__ unsigned short pbkt[PCH];
    int t = threadIdx.x;
    int e0 = blockIdx.x * PCH;
    int nE = EE - e0; if (nE > PCH) nE = PCH;

    for (int i = t; i < NB; i += 256) { hist[i] = 0; cnt2[i] = 0; }
    __syncthreads();

    int mys[16], myd[16];
    #pragma unroll
    for (int i = 0; i < 16; ++i) {
        int idx = i * 256 + t;
        if (idx < nE) {
            mys[i] = ei[e0 + idx];
            myd[i] = ei[EE + e0 + idx];
            atomicAdd(&hist[myd[i] >> 8], 1);
        } else myd[i] = -1;
    }
    __syncthreads();

    scanbuf[t]       = (t < NB) ? hist[t] : 0;
    scanbuf[t + 256] = (t + 256 < NB) ? hist[t + 256] : 0;
    __syncthreads();
    for (int d = 1; d < 512; d <<= 1) {
        int a0 = (t >= d) ? scanbuf[t - d] : 0;
        int a1 = ((t + 256) >= d) ? scanbuf[t + 256 - d] : 0;
        __syncthreads();
        scanbuf[t] += a0;
        scanbuf[t + 256] += a1;
        __syncthreads();
    }
    if (t < NB)       base[t]       = scanbuf[t] - hist[t];
    if (t + 256 < NB) base[t + 256] = scanbuf[t + 256] - hist[t + 256];
    __syncthreads();

    #pragma unroll
    for (int i = 0; i < 16; ++i) {
        if (myd[i] >= 0) {
            int b = myd[i] >> 8;
            int p = base[b] + atomicAdd(&cnt2[b], 1);
            pairs[p] = (unsigned)mys[i] | ((unsigned)(myd[i] & 255) << 17);
            pbkt[p] = (unsigned short)b;
        }
    }
    __syncthreads();
    for (int i = t; i < NB; i += 256)
        if (hist[i]) gbase[i] = atomicAdd(&bcur[i], hist[i]);
    __syncthreads();
    for (int p = t; p < nE; p += 256) {
        int b = pbkt[p];
        stage[gbase[b] + (p - base[b])] = pairs[p];
    }
}

// ============ per-bucket CSR: adj + offs in LDS, adj SORTED BY SRC ============
// R10: per-node insertion sort of each adj segment (src ascending). All lane
// groups then sweep src-space together during the gather -> instantaneous
// working set ~2.6MB (sliding window) instead of uniform 12.8MB -> scattered
// reads become XCD-L2 hits instead of L3/fabric misses. Edge order per node
// changes, but the prior order was already atomic-arrival-nondeterministic;
// fp32 reorder is within tolerance (passes every round).
__global__ __launch_bounds__(256) void bucket_csr_k(const unsigned int* __restrict__ stage,
                                                    const int* __restrict__ bo,
                                                    int* __restrict__ adj,
                                                    int* __restrict__ offs) {
    __shared__ int deg[256];
    __shared__ int sb[256];
    __shared__ int nb_[256];
    __shared__ int c2[256];
    __shared__ int loc[BCAP];
    int b = blockIdx.x;
    int s0 = bo[b], s1 = bo[b + 1];
    int cnt = s1 - s0;
    int t = threadIdx.x;

    deg[t] = 0;
    __syncthreads();
    for (int i = t; i < cnt; i += 256) atomicAdd(&deg[(stage[s0 + i] >> 17) & 255], 1);
    __syncthreads();
    sb[t] = deg[t];
    __syncthreads();
    for (int d = 1; d < 256; d <<= 1) {
        int a = (t >= d) ? sb[t - d] : 0;
        __syncthreads();
        sb[t] += a;
        __syncthreads();
    }
    int nbase = sb[t] - deg[t];
    nb_[t] = nbase;
    c2[t] = 0;
    offs[b * 256 + t] = s0 + nbase;
    __syncthreads();

    if (cnt <= BCAP) {
        for (int i = t; i < cnt; i += 256) {
            unsigned int pr = stage[s0 + i];
            int ln = (pr >> 17) & 255;
            int p = nb_[ln] + atomicAdd(&c2[ln], 1);
            loc[p] = (int)(pr & 0x1FFFF);
        }
        __syncthreads();
        // per-node insertion sort (thread t owns node t's segment; ~deg^2/2 LDS ops)
        {
            int st = nb_[t], en = st + deg[t];
            for (int i = st + 1; i < en; ++i) {
                int v = loc[i];
                int k = i - 1;
                while (k >= st && loc[k] > v) { loc[k + 1] = loc[k]; --k; }
                loc[k + 1] = v;
            }
        }
        __syncthreads();
        for (int i = t; i < cnt; i += 256) adj[s0 + i] = loc[i];
    } else {            // statistically unreachable fallback (unsorted; still correct)
        for (int i = t; i < cnt; i += 256) {
            unsigned int pr = stage[s0 + i];
            int ln = (pr >> 17) & 255;
            int p = nb_[ln] + atomicAdd(&c2[ln], 1);
            adj[s0 + p] = (int)(pr & 0x1FFFF);
        }
    }
}

// ========== K1 v9: R8 gather (adj-prefetch pipeline) over SORTED adj ==========
// R9 post-mortem: glds pipeline's vmcnt accounting was polluted by adj vector
// loads -> effective depth ~2 (same as allocator gives) + LDS round-trip
// overhead: 58->71.7us. Reverted to the verified R8 body (58us). The new
// lever is upstream: sorted adj turns L3-miss lines into L2 hits.
__global__ __launch_bounds__(512, 8) void layer1_k(
    const unsigned short* __restrict__ hb, const int* __restrict__ adj,
    const int* __restrict__ offs, const float* __restrict__ epsArr, int l,
    const unsigned short* __restrict__ wtm, const float* __restrict__ bias,
    unsigned short* __restrict__ z1, float* __restrict__ stats1,
    float* __restrict__ stats2z)
{
    __shared__ unsigned short aLDS[64 * 64];   // 8KB, XOR-swizzled 16B units
    const int t = threadIdx.x;
    const int lane = t & 63;
    const int w = t >> 6;          // 0..7
    const int n15 = lane & 15;
    const int quad = lane >> 4;

    if (blockIdx.x < SC && t < 128) stats2z[blockIdx.x * 128 + t] = 0.f;

    const float epsv = 1.0f + epsArr[l];
    const int c8 = lane & 7;
    // ---- gather: one row per 8-lane group, adj software-pipelined ----
    {
        int lr = w * 8 + (lane >> 3);
        int n = blockIdx.x * 64 + lr;
        float acc[8] = {0.f,0.f,0.f,0.f,0.f,0.f,0.f,0.f};
        if (n < NN) {
            uint4 a = *(const uint4*)(hb + (size_t)n * DD + c8 * 8);
            unpack8(a, acc);
            #pragma unroll
            for (int j2 = 0; j2 < 8; ++j2) acc[j2] *= epsv;
            int j = offs[n], end = offs[n + 1];
            if (j < end) {
                int e1 = end - 1;
                // prologue: first adj batch (clamped)
                int a0 = adj[j];
                int a1 = adj[(j + 1 < end) ? j + 1 : e1];
                int a2 = adj[(j + 2 < end) ? j + 2 : e1];
                int a3 = adj[(j + 3 < end) ? j + 3 : e1];
                #pragma unroll 1
                while (j < end) {
                    // issue hb loads of current batch (independent)
                    uint4 v0 = *(const uint4*)(hb + (size_t)a0 * DD + c8 * 8);
                    uint4 v1 = *(const uint4*)(hb + (size_t)a1 * DD + c8 * 8);
                    uint4 v2 = *(const uint4*)(hb + (size_t)a2 * DD + c8 * 8);
                    uint4 v3 = *(const uint4*)(hb + (size_t)a3 * DD + c8 * 8);
                    // prefetch next adj batch (addresses induction-derived)
                    int jn = j + 4;
                    int b0 = adj[(jn     < end) ? jn     : e1];
                    int b1 = adj[(jn + 1 < end) ? jn + 1 : e1];
                    int b2 = adj[(jn + 2 < end) ? jn + 2 : e1];
                    int b3 = adj[(jn + 3 < end) ? jn + 3 : e1];
                    // accumulate current batch (predicated tail, adj order)
                    int rem = end - j;
                    acc8(v0, acc);
                    if (rem > 1) acc8(v1, acc);
                    if (rem > 2) acc8(v2, acc);
                    if (rem > 3) acc8(v3, acc);
                    a0 = b0; a1 = b1; a2 = b2; a3 = b3;
                    j = jn;
                }
            }
        }
        int pu = c8 ^ (lr & 7);
        *(uint4*)(aLDS + lr * 64 + pu * 8) = pack8(acc);
    }

    // ---- B fragments for this wave's 2 column tiles (issued before barrier) ----
    const int rt = w & 3;          // row tile (16 rows)
    const int cb = (w >> 2) * 2;   // first of 2 column tiles
    U16 bfr[2][2];
    #pragma unroll
    for (int ci = 0; ci < 2; ++ci)
        #pragma unroll
        for (int ks = 0; ks < 2; ++ks)
            bfr[ci][ks].u = *(const uint4*)(wtm + (size_t)((cb + ci) * 16 + n15) * 64 + ks * 32 + quad * 8);

    __syncthreads();               // A-rows in LDS are cross-wave

    // ---- A fragments from LDS (swizzled) ----
    U16 afr[2];
    int lr2 = rt * 16 + n15;
    #pragma unroll
    for (int ks = 0; ks < 2; ++ks) {
        int pu = (ks * 4 + quad) ^ (lr2 & 7);
        afr[ks].u = *(const uint4*)(aLDS + lr2 * 64 + pu * 8);
    }

    const int rowg0 = blockIdx.x * 64 + rt * 16;
    const int copy = blockIdx.x & (SC - 1);
    #pragma unroll
    for (int ci = 0; ci < 2; ++ci) {
        int ct = cb + ci;
        f32x4 acc = {0.f, 0.f, 0.f, 0.f};
        acc = __builtin_amdgcn_mfma_f32_16x16x32_bf16(afr[0].h, bfr[ci][0].h, acc, 0, 0, 0);
        acc = __builtin_amdgcn_mfma_f32_16x16x32_bf16(afr[1].h, bfr[ci][1].h, acc, 0, 0, 0);
        int col = ct * 16 + n15;
        float bcol = bias[col];
        float s = 0.f, ss = 0.f;
        #pragma unroll
        for (int r = 0; r < 4; ++r) {
            int rg = rowg0 + quad * 4 + r;
            float v = acc[r] + bcol;
            if (rg < NN) {
                z1[(size_t)rg * DD + col] = f2bf_rne(v);
                s += v;
                ss = fmaf(v, v, ss);
            }
        }
        s  += __shfl_xor(s, 16, 64);  s  += __shfl_xor(s, 32, 64);
        ss += __shfl_xor(ss, 16, 64); ss += __shfl_xor(ss, 32, 64);
        if (lane < 16) {
            atomicAdd(&stats1[copy * 128 + ct * 16 + lane], s);
            atomicAdd(&stats1[copy * 128 + 64 + ct * 16 + lane], ss);
        }
    }
}

// ========== K2: inline BN1 + MFMA GEMM2 + stats2 ==========
__global__ __launch_bounds__(256) void layer2_k(
    const unsigned short* __restrict__ z1, const float* __restrict__ stats1,
    const float* __restrict__ gamma, const float* __restrict__ beta, int off,
    const unsigned short* __restrict__ wtm, const float* __restrict__ bias,
    unsigned short* __restrict__ z2, float* __restrict__ stats2)
{
    __shared__ float ssS[128];
    const int t = threadIdx.x;
    const int lane = t & 63;
    const int w = t >> 6;
    const int n15 = lane & 15;
    const int quad = lane >> 4;
    const int rowg0 = blockIdx.x * 64 + w * 16;

    // ---- issue independent global loads BEFORE the stats barrier ----
    U16 bfr[4][2];
    #pragma unroll
    for (int ct = 0; ct < 4; ++ct)
        #pragma unroll
        for (int ks = 0; ks < 2; ++ks)
            bfr[ct][ks].u = *(const uint4*)(wtm + (size_t)(ct * 16 + n15) * 64 + ks * 32 + quad * 8);

    int arow = rowg0 + n15;
    int arowc = (arow < NN) ? arow : (NN - 1);
    uint4 raw[2];
    #pragma unroll
    for (int ks = 0; ks < 2; ++ks)
        raw[ks] = *(const uint4*)(z1 + (size_t)arowc * DD + ks * 32 + quad * 8);

    if (t < 64) {
        float S = 0.f, SS = 0.f;
        #pragma unroll
        for (int c = 0; c < SC; ++c) { S += stats1[c * 128 + t]; SS += stats1[c * 128 + 64 + t]; }
        float inv_n = 1.0f / (float)NN;
        float mean = S * inv_n;
        float var  = SS * inv_n - mean * mean;
        float sc = gamma[off + t] * rsqrtf(var + 1e-5f);
        ssS[t] = sc;
        ssS[64 + t] = beta[off + t] - sc * mean;
    }
    __syncthreads();

    U16 afr[2];
    #pragma unroll
    for (int ks = 0; ks < 2; ++ks) {
        float f[8];
        unpack8(raw[ks], f);
        int k0 = ks * 32 + quad * 8;
        #pragma unroll
        for (int j = 0; j < 8; ++j)
            f[j] = fmaxf(fmaf(ssS[k0 + j], f[j], ssS[64 + k0 + j]), 0.f);
        afr[ks].u = pack8(f);
    }

    const int copy = blockIdx.x & (SC - 1);
    #pragma unroll
    for (int ct = 0; ct < 4; ++ct) {
        f32x4 acc = {0.f, 0.f, 0.f, 0.f};
        acc = __builtin_amdgcn_mfma_f32_16x16x32_bf16(afr[0].h, bfr[ct][0].h, acc, 0, 0, 0);
        acc = __builtin_amdgcn_mfma_f32_16x16x32_bf16(afr[1].h, bfr[ct][1].h, acc, 0, 0, 0);
        int col = ct * 16 + n15;
        float bcol = bias[col];
        float s = 0.f, ss = 0.f;
        #pragma unroll
        for (int r = 0; r < 4; ++r) {
            int rg = rowg0 + quad * 4 + r;
            float v = acc[r] + bcol;
            if (rg < NN) {
                z2[(size_t)rg * DD + col] = f2bf_rne(v);
                s += v;
                ss = fmaf(v, v, ss);
            }
        }
        s  += __shfl_xor(s, 16, 64);  s  += __shfl_xor(s, 32, 64);
        ss += __shfl_xor(ss, 16, 64); ss += __shfl_xor(ss, 32, 64);
        if (lane < 16) {
            atomicAdd(&stats2[copy * 128 + ct * 16 + lane], s);
            atomicAdd(&stats2[copy * 128 + 64 + ct * 16 + lane], ss);
        }
    }
}

// ========== K3: inline BN2 + ReLU + hb write + segmented pool ==========
__global__ __launch_bounds__(256) void layer3_k(
    const unsigned short* __restrict__ z2, const float* __restrict__ stats2,
    const float* __restrict__ gamma, const float* __restrict__ beta, int off,
    const int* __restrict__ batch, unsigned short* __restrict__ hout,
    float* __restrict__ pooled, float* __restrict__ stats1z)
{
    __shared__ float ssS[128];
    int t = threadIdx.x;
    if (blockIdx.x < SC && t < 128) stats1z[blockIdx.x * 128 + t] = 0.f;
    if (t < 64) {
        float S = 0.f, SS = 0.f;
        #pragma unroll
        for (int c = 0; c < SC; ++c) { S += stats2[c * 128 + t]; SS += stats2[c * 128 + 64 + t]; }
        float inv_n = 1.0f / (float)NN;
        float mean = S * inv_n;
        float var  = SS * inv_n - mean * mean;
        float sc = gamma[off + t] * rsqrtf(var + 1e-5f);
        ssS[t] = sc;
        ssS[64 + t] = beta[off + t] - sc * mean;
    }
    __syncthreads();

    int f = t & 63;
    int q = t >> 6;
    int n0 = blockIdx.x * 64 + q * 16;
    int nmax = NN - n0; if (nmax > 16) nmax = 16;
    float sc = ssS[f], sh = ssS[64 + f];
    float acc = 0.f;
    int curg = -1;
    #pragma unroll 4
    for (int i = 0; i < nmax; ++i) {
        int n = n0 + i;
        int g = batch[n];
        if (g != curg) {
            if (curg >= 0) atomicAdd(&pooled[(size_t)curg * DD + f], acc);
            acc = 0.f; curg = g;
        }
        float v = bf2f(z2[(size_t)n * DD + f]);
        v = fmaxf(fmaf(sc, v, sh), 0.f);
        hout[(size_t)n * DD + f] = f2bf_rne(v);
        acc += v;
    }
    if (curg >= 0) atomicAdd(&pooled[(size_t)curg * DD + f], acc);
}

// ================= jumping-knowledge readout =================
__global__ void readout_k(const float* __restrict__ pooled,
                          const float* __restrict__ Wp, const float* __restrict__ bp,
                          float* __restrict__ out)
{
    int gc = blockIdx.x * blockDim.x + threadIdx.x;
    if (gc >= GG * CC) return;
    int g = gc / CC, c = gc - g * CC;
    float acc = 0.f;
    for (int l = 0; l < LL; ++l) {
        acc += bp[l * CC + c];
        const float* p  = pooled + ((size_t)l * GG + g) * DD;
        const float* wv = Wp + (size_t)l * DD * CC + c;
        #pragma unroll 8
        for (int f = 0; f < DD; ++f) acc = fmaf(p[f], wv[f * CC], acc);
    }
    out[gc] = acc;
}

extern "C" void kernel_launch(void* const* d_in, const int* in_sizes, int n_in,
                              void* d_out, int out_size, void* d_ws, size_t ws_size,
                              hipStream_t stream) {
    const float* x     = (const float*)d_in[0];
    const int*   ei    = (const int*)d_in[1];
    const int*   batch = (const int*)d_in[2];
    const float* eps   = (const float*)d_in[3];
    const float* W1    = (const float*)d_in[4];
    const float* b1    = (const float*)d_in[5];
    const float* g1    = (const float*)d_in[6];
    const float* be1   = (const float*)d_in[7];
    const float* W2    = (const float*)d_in[8];
    const float* b2    = (const float*)d_in[9];
    const float* gout  = (const float*)d_in[10];
    const float* beout = (const float*)d_in[11];
    const float* Wp    = (const float*)d_in[12];
    const float* bp    = (const float*)d_in[13];
    float* out = (float*)d_out;

    // ---- workspace layout (16B-aligned sections; bh adjacent to pooled so
    //      one memset covers bh+pooled+stats) ----
    unsigned int* stage = (unsigned int*)d_ws;          // EE*4
    int* adj   = (int*)(stage + EE);                    // EE*4
    int* offs  = adj + EE;                              // (NPAD+256)
    int* bo    = offs + NPAD + 256;                     // 400
    int* bcur  = bo + 400;                              // 400
    int* bh    = bcur + 400;                            // 400
    float* pooled = (float*)(bh + 400);                 // LL*GG*DD
    float* stats1 = pooled + (size_t)LL * GG * DD;      // SC*128
    float* stats2 = stats1 + SC * 128;                  // SC*128
    unsigned short* hb  = (unsigned short*)(stats2 + SC * 128);
    unsigned short* z1b = hb + N64;
    unsigned short* z2b = z1b + N64;
    unsigned short* wt  = z2b + N64;                    // 8*4096

    // ---- single memset: bh + pooled + stats1 + stats2 ----
    hipMemsetAsync(bh, 0, (400 + (size_t)LL * GG * DD + 2 * SC * 128) * sizeof(int), stream);
    // ---- fused prep (x->bf16 + pool0 | W^T | edge hist) ----
    prep_all_k<<<PREPG + 8 + 512, 256, 0, stream>>>(x, batch, hb, pooled, W1, W2, wt, ei, bh);
    bscan_k<<<1, 512, 0, stream>>>(bh, bo, bcur);
    partition_k<<<(EE + PCH - 1) / PCH, 256, 0, stream>>>(ei, bcur, stage);
    bucket_csr_k<<<NB, 256, 0, stream>>>(stage, bo, adj, offs);

    const int gemm_grid = (NN + 63) / 64;
    const int node_grid = (NN + 63) / 64;
    for (int l = 0; l < LL - 1; ++l) {
        layer1_k<<<gemm_grid, 512, 0, stream>>>(
            hb, adj, offs, eps, l, wt + (size_t)l * 4096, b1 + l * DD, z1b, stats1, stats2);
        layer2_k<<<gemm_grid, 256, 0, stream>>>(
            z1b, stats1, g1, be1, l * DD, wt + (size_t)(4 + l) * 4096, b2 + l * DD, z2b, stats2);
        layer3_k<<<node_grid, 256, 0, stream>>>(
            z2b, stats2, gout, beout, l * DD, batch, hb,
            pooled + (size_t)(l + 1) * GG * DD, stats1);
    }
    readout_k<<<(GG * CC + 255) / 256, 256, 0, stream>>>(pooled, Wp, bp, out);
}

// Round 11
// 555.705 us; speedup vs baseline: 1.1461x; 1.1096x over previous
//
#include <hip/hip_runtime.h>

#define NN 100000
#define EE 1600000
#define DD 64
#define CC 10
#define GG 512
#define LL 5
#define NPAD 100352            // 392*256
#define N64 (NN * DD)
#define NB 392                 // coarse buckets (256 nodes each)
#define PCH 4096               // edges per partition block
#define BCAP 6144              // per-bucket LDS capacity (mean 4082, >30 sigma)
#define SC 8                   // BN stats shadow copies
#define PREPG 1563             // (NN+63)/64

typedef short bf16x8 __attribute__((ext_vector_type(8)));
typedef float f32x4  __attribute__((ext_vector_type(4)));
union U16 { uint4 u; bf16x8 h; };

__device__ __forceinline__ float bits2f(unsigned int b) { return __uint_as_float(b); }
__device__ __forceinline__ float bf2f(unsigned short s) { return __uint_as_float((unsigned int)s << 16); }
__device__ __forceinline__ unsigned short f2bf_rne(float v) {
    unsigned int b = __float_as_uint(v);
    return (unsigned short)((b + 0x7fffu + ((b >> 16) & 1u)) >> 16);
}
__device__ __forceinline__ void unpack8(uint4 u, float* f) {
    f[0] = bits2f(u.x << 16); f[1] = bits2f(u.x & 0xffff0000u);
    f[2] = bits2f(u.y << 16); f[3] = bits2f(u.y & 0xffff0000u);
    f[4] = bits2f(u.z << 16); f[5] = bits2f(u.z & 0xffff0000u);
    f[6] = bits2f(u.w << 16); f[7] = bits2f(u.w & 0xffff0000u);
}
__device__ __forceinline__ uint4 pack8(const float* f) {
    uint4 u;
    u.x = (unsigned int)f2bf_rne(f[0]) | ((unsigned int)f2bf_rne(f[1]) << 16);
    u.y = (unsigned int)f2bf_rne(f[2]) | ((unsigned int)f2bf_rne(f[3]) << 16);
    u.z = (unsigned int)f2bf_rne(f[4]) | ((unsigned int)f2bf_rne(f[5]) << 16);
    u.w = (unsigned int)f2bf_rne(f[6]) | ((unsigned int)f2bf_rne(f[7]) << 16);
    return u;
}
__device__ __forceinline__ void acc8(uint4 u, float* a) {
    float t[8];
    unpack8(u, t);
    #pragma unroll
    for (int k = 0; k < 8; ++k) a[k] += t[k];
}

// ======== fused prep: x->bf16 + layer-0 pool | W transpose | edge hist ========
__global__ __launch_bounds__(256) void prep_all_k(
    const float* __restrict__ x, const int* __restrict__ batch,
    unsigned short* __restrict__ hbuf, float* __restrict__ pooled,
    const float* __restrict__ W1, const float* __restrict__ W2,
    unsigned short* __restrict__ wt,
    const int* __restrict__ ei, int* __restrict__ bh)
{
    __shared__ int cnt[NB];
    const int bid = blockIdx.x;
    const int t = threadIdx.x;
    if (bid < PREPG) {
        int f = t & 63;
        int q = t >> 6;
        int n0 = bid * 64 + q * 16;
        int nmax = NN - n0; if (nmax > 16) nmax = 16;
        float acc = 0.f;
        int curg = -1;
        #pragma unroll 4
        for (int i = 0; i < nmax; ++i) {
            int n = n0 + i;
            int g = batch[n];
            if (g != curg) {
                if (curg >= 0) atomicAdd(&pooled[(size_t)curg * DD + f], acc);
                acc = 0.f; curg = g;
            }
            float v = x[(size_t)n * DD + f];
            hbuf[(size_t)n * DD + f] = f2bf_rne(v);
            acc += v;
        }
        if (curg >= 0) atomicAdd(&pooled[(size_t)curg * DD + f], acc);
    } else if (bid < PREPG + 8) {
        int mat = bid - PREPG;
        const float* src = (mat < 4) ? (W1 + (size_t)mat * 4096)
                                     : (W2 + (size_t)(mat - 4) * 4096);
        for (int idx = t; idx < 4096; idx += 256) {
            int c = idx >> 6, k = idx & 63;
            wt[(size_t)mat * 4096 + c * 64 + k] = f2bf_rne(src[k * 64 + c]);
        }
    } else {
        int hid = bid - PREPG - 8;          // 0..511
        for (int i = t; i < NB; i += 256) cnt[i] = 0;
        __syncthreads();
        for (int e = hid * 256 + t; e < EE; e += 512 * 256)
            atomicAdd(&cnt[ei[EE + e] >> 8], 1);
        __syncthreads();
        for (int i = t; i < NB; i += 256)
            if (cnt[i]) atomicAdd(&bh[i], cnt[i]);
    }
}

// ================= coarse scan =================
__global__ __launch_bounds__(512) void bscan_k(const int* __restrict__ bh,
                                               int* __restrict__ bo,
                                               int* __restrict__ bcur) {
    __shared__ int s[512];
    int t = threadIdx.x;
    int v = (t < NB) ? bh[t] : 0;
    s[t] = v;
    __syncthreads();
    for (int d = 1; d < 512; d <<= 1) {
        int a = (t >= d) ? s[t - d] : 0;
        __syncthreads();
        s[t] += a;
        __syncthreads();
    }
    int excl = s[t] - v;
    if (t < NB) { bo[t] = excl; bcur[t] = excl; }
    if (t == NB - 1) bo[NB] = excl + v;
}

// ============ partition edges into bucket-contiguous staging ============
// stage entry: src (bits 0..16) | dst-local-in-bucket (bits 17..24)
__global__ __launch_bounds__(256) void partition_k(const int* __restrict__ ei,
                                                   int* __restrict__ bcur,
                                                   unsigned int* __restrict__ stage) {
    __shared__ int hist[NB];
    __shared__ int base[NB];
    __shared__ int gbase[NB];
    __shared__ int cnt2[NB];
    __shared__ int scanbuf[512];
    __shared__ unsigned int pairs[PCH];
    __shared__ unsigned short pbkt[PCH];
    int t = threadIdx.x;
    int e0 = blockIdx.x * PCH;
    int nE = EE - e0; if (nE > PCH) nE = PCH;

    for (int i = t; i < NB; i += 256) { hist[i] = 0; cnt2[i] = 0; }
    __syncthreads();

    int mys[16], myd[16];
    #pragma unroll
    for (int i = 0; i < 16; ++i) {
        int idx = i * 256 + t;
        if (idx < nE) {
            mys[i] = ei[e0 + idx];
            myd[i] = ei[EE + e0 + idx];
            atomicAdd(&hist[myd[i] >> 8], 1);
        } else myd[i] = -1;
    }
    __syncthreads();

    scanbuf[t]       = (t < NB) ? hist[t] : 0;
    scanbuf[t + 256] = (t + 256 < NB) ? hist[t + 256] : 0;
    __syncthreads();
    for (int d = 1; d < 512; d <<= 1) {
        int a0 = (t >= d) ? scanbuf[t - d] : 0;
        int a1 = ((t + 256) >= d) ? scanbuf[t + 256 - d] : 0;
        __syncthreads();
        scanbuf[t] += a0;
        scanbuf[t + 256] += a1;
        __syncthreads();
    }
    if (t < NB)       base[t]       = scanbuf[t] - hist[t];
    if (t + 256 < NB) base[t + 256] = scanbuf[t + 256] - hist[t + 256];
    __syncthreads();

    #pragma unroll
    for (int i = 0; i < 16; ++i) {
        if (myd[i] >= 0) {
            int b = myd[i] >> 8;
            int p = base[b] + atomicAdd(&cnt2[b], 1);
            pairs[p] = (unsigned)mys[i] | ((unsigned)(myd[i] & 255) << 17);
            pbkt[p] = (unsigned short)b;
        }
    }
    __syncthreads();
    for (int i = t; i < NB; i += 256)
        if (hist[i]) gbase[i] = atomicAdd(&bcur[i], hist[i]);
    __syncthreads();
    for (int p = t; p < nE; p += 256) {
        int b = pbkt[p];
        stage[gbase[b] + (p - base[b])] = pairs[p];
    }
}

// ============ per-bucket CSR: adj + offs, all in LDS (R8 body, no sort) ============
// R10 post-mortem: per-node insertion sort cost ~44us (serial divergent LDS
// chain) for only -5.5% FETCH (sorted window ~6MB > 4MiB L2) -- net loser.
__global__ __launch_bounds__(256) void bucket_csr_k(const unsigned int* __restrict__ stage,
                                                    const int* __restrict__ bo,
                                                    int* __restrict__ adj,
                                                    int* __restrict__ offs) {
    __shared__ int deg[256];
    __shared__ int sb[256];
    __shared__ int nb_[256];
    __shared__ int c2[256];
    __shared__ int loc[BCAP];
    int b = blockIdx.x;
    int s0 = bo[b], s1 = bo[b + 1];
    int cnt = s1 - s0;
    int t = threadIdx.x;

    deg[t] = 0;
    __syncthreads();
    for (int i = t; i < cnt; i += 256) atomicAdd(&deg[(stage[s0 + i] >> 17) & 255], 1);
    __syncthreads();
    sb[t] = deg[t];
    __syncthreads();
    for (int d = 1; d < 256; d <<= 1) {
        int a = (t >= d) ? sb[t - d] : 0;
        __syncthreads();
        sb[t] += a;
        __syncthreads();
    }
    int nbase = sb[t] - deg[t];
    nb_[t] = nbase;
    c2[t] = 0;
    offs[b * 256 + t] = s0 + nbase;
    __syncthreads();

    if (cnt <= BCAP) {
        for (int i = t; i < cnt; i += 256) {
            unsigned int pr = stage[s0 + i];
            int ln = (pr >> 17) & 255;
            int p = nb_[ln] + atomicAdd(&c2[ln], 1);
            loc[p] = (int)(pr & 0x1FFFF);
        }
        __syncthreads();
        for (int i = t; i < cnt; i += 256) adj[s0 + i] = loc[i];
    } else {            // statistically unreachable fallback
        for (int i = t; i < cnt; i += 256) {
            unsigned int pr = stage[s0 + i];
            int ln = (pr >> 17) & 255;
            int p = nb_[ln] + atomicAdd(&c2[ln], 1);
            adj[s0 + p] = (int)(pr & 0x1FFFF);
        }
    }
}

// ========== K1: R8 gather (verified 58us) -> LDS -> MFMA GEMM1 + stats1 ==========
__global__ __launch_bounds__(512, 8) void layer1_k(
    const unsigned short* __restrict__ hb, const int* __restrict__ adj,
    const int* __restrict__ offs, const float* __restrict__ epsArr, int l,
    const unsigned short* __restrict__ wtm, const float* __restrict__ bias,
    unsigned short* __restrict__ z1, float* __restrict__ stats1,
    float* __restrict__ stats2z)
{
    __shared__ unsigned short aLDS[64 * 64];   // 8KB, XOR-swizzled 16B units
    const int t = threadIdx.x;
    const int lane = t & 63;
    const int w = t >> 6;          // 0..7
    const int n15 = lane & 15;
    const int quad = lane >> 4;

    if (blockIdx.x < SC && t < 128) stats2z[blockIdx.x * 128 + t] = 0.f;

    const float epsv = 1.0f + epsArr[l];
    const int c8 = lane & 7;
    // ---- gather: one row per 8-lane group, adj software-pipelined ----
    {
        int lr = w * 8 + (lane >> 3);
        int n = blockIdx.x * 64 + lr;
        float acc[8] = {0.f,0.f,0.f,0.f,0.f,0.f,0.f,0.f};
        if (n < NN) {
            uint4 a = *(const uint4*)(hb + (size_t)n * DD + c8 * 8);
            unpack8(a, acc);
            #pragma unroll
            for (int j2 = 0; j2 < 8; ++j2) acc[j2] *= epsv;
            int j = offs[n], end = offs[n + 1];
            if (j < end) {
                int e1 = end - 1;
                int a0 = adj[j];
                int a1 = adj[(j + 1 < end) ? j + 1 : e1];
                int a2 = adj[(j + 2 < end) ? j + 2 : e1];
                int a3 = adj[(j + 3 < end) ? j + 3 : e1];
                #pragma unroll 1
                while (j < end) {
                    uint4 v0 = *(const uint4*)(hb + (size_t)a0 * DD + c8 * 8);
                    uint4 v1 = *(const uint4*)(hb + (size_t)a1 * DD + c8 * 8);
                    uint4 v2 = *(const uint4*)(hb + (size_t)a2 * DD + c8 * 8);
                    uint4 v3 = *(const uint4*)(hb + (size_t)a3 * DD + c8 * 8);
                    int jn = j + 4;
                    int b0 = adj[(jn     < end) ? jn     : e1];
                    int b1 = adj[(jn + 1 < end) ? jn + 1 : e1];
                    int b2 = adj[(jn + 2 < end) ? jn + 2 : e1];
                    int b3 = adj[(jn + 3 < end) ? jn + 3 : e1];
                    int rem = end - j;
                    acc8(v0, acc);
                    if (rem > 1) acc8(v1, acc);
                    if (rem > 2) acc8(v2, acc);
                    if (rem > 3) acc8(v3, acc);
                    a0 = b0; a1 = b1; a2 = b2; a3 = b3;
                    j = jn;
                }
            }
        }
        int pu = c8 ^ (lr & 7);
        *(uint4*)(aLDS + lr * 64 + pu * 8) = pack8(acc);
    }

    // ---- B fragments for this wave's 2 column tiles (issued before barrier) ----
    const int rt = w & 3;          // row tile (16 rows)
    const int cb = (w >> 2) * 2;   // first of 2 column tiles
    U16 bfr[2][2];
    #pragma unroll
    for (int ci = 0; ci < 2; ++ci)
        #pragma unroll
        for (int ks = 0; ks < 2; ++ks)
            bfr[ci][ks].u = *(const uint4*)(wtm + (size_t)((cb + ci) * 16 + n15) * 64 + ks * 32 + quad * 8);

    __syncthreads();               // A-rows in LDS are cross-wave

    // ---- A fragments from LDS (swizzled) ----
    U16 afr[2];
    int lr2 = rt * 16 + n15;
    #pragma unroll
    for (int ks = 0; ks < 2; ++ks) {
        int pu = (ks * 4 + quad) ^ (lr2 & 7);
        afr[ks].u = *(const uint4*)(aLDS + lr2 * 64 + pu * 8);
    }

    const int rowg0 = blockIdx.x * 64 + rt * 16;
    const int copy = blockIdx.x & (SC - 1);
    #pragma unroll
    for (int ci = 0; ci < 2; ++ci) {
        int ct = cb + ci;
        f32x4 acc = {0.f, 0.f, 0.f, 0.f};
        acc = __builtin_amdgcn_mfma_f32_16x16x32_bf16(afr[0].h, bfr[ci][0].h, acc, 0, 0, 0);
        acc = __builtin_amdgcn_mfma_f32_16x16x32_bf16(afr[1].h, bfr[ci][1].h, acc, 0, 0, 0);
        int col = ct * 16 + n15;
        float bcol = bias[col];
        float s = 0.f, ss = 0.f;
        #pragma unroll
        for (int r = 0; r < 4; ++r) {
            int rg = rowg0 + quad * 4 + r;
            float v = acc[r] + bcol;
            if (rg < NN) {
                z1[(size_t)rg * DD + col] = f2bf_rne(v);
                s += v;
                ss = fmaf(v, v, ss);
            }
        }
        s  += __shfl_xor(s, 16, 64);  s  += __shfl_xor(s, 32, 64);
        ss += __shfl_xor(ss, 16, 64); ss += __shfl_xor(ss, 32, 64);
        if (lane < 16) {
            atomicAdd(&stats1[copy * 128 + ct * 16 + lane], s);
            atomicAdd(&stats1[copy * 128 + 64 + ct * 16 + lane], ss);
        }
    }
}

// ========== K2 v2: inline BN1 + MFMA GEMM2 + stats2, 256 rows/block ==========
// R11: 4x work per block (grid 1563->391). wt fragments + stats->ssS loaded
// ONCE per block; BN-stats accumulated in regs across 4 tiles, one
// shuffle-reduce + atomic set per block (4x fewer stats atomics).
__global__ __launch_bounds__(256) void layer2_k(
    const unsigned short* __restrict__ z1, const float* __restrict__ stats1,
    const float* __restrict__ gamma, const float* __restrict__ beta, int off,
    const unsigned short* __restrict__ wtm, const float* __restrict__ bias,
    unsigned short* __restrict__ z2, float* __restrict__ stats2)
{
    __shared__ float ssS[128];
    const int t = threadIdx.x;
    const int lane = t & 63;
    const int w = t >> 6;
    const int n15 = lane & 15;
    const int quad = lane >> 4;
    const int base0 = blockIdx.x * 256;

    // ---- wt fragments once per block, issued before the stats barrier ----
    U16 bfr[4][2];
    #pragma unroll
    for (int ct = 0; ct < 4; ++ct)
        #pragma unroll
        for (int ks = 0; ks < 2; ++ks)
            bfr[ct][ks].u = *(const uint4*)(wtm + (size_t)(ct * 16 + n15) * 64 + ks * 32 + quad * 8);

    if (t < 64) {
        float S = 0.f, SS = 0.f;
        #pragma unroll
        for (int c = 0; c < SC; ++c) { S += stats1[c * 128 + t]; SS += stats1[c * 128 + 64 + t]; }
        float inv_n = 1.0f / (float)NN;
        float mean = S * inv_n;
        float var  = SS * inv_n - mean * mean;
        float sc = gamma[off + t] * rsqrtf(var + 1e-5f);
        ssS[t] = sc;
        ssS[64 + t] = beta[off + t] - sc * mean;
    }
    __syncthreads();

    float sacc[4]  = {0.f, 0.f, 0.f, 0.f};
    float ssacc[4] = {0.f, 0.f, 0.f, 0.f};
    #pragma unroll 1
    for (int ti = 0; ti < 4; ++ti) {
        const int rowg0 = base0 + ti * 64 + w * 16;
        int arow = rowg0 + n15;
        int arowc = (arow < NN) ? arow : (NN - 1);
        uint4 raw[2];
        #pragma unroll
        for (int ks = 0; ks < 2; ++ks)
            raw[ks] = *(const uint4*)(z1 + (size_t)arowc * DD + ks * 32 + quad * 8);

        U16 afr[2];
        #pragma unroll
        for (int ks = 0; ks < 2; ++ks) {
            float f[8];
            unpack8(raw[ks], f);
            int k0 = ks * 32 + quad * 8;
            #pragma unroll
            for (int j = 0; j < 8; ++j)
                f[j] = fmaxf(fmaf(ssS[k0 + j], f[j], ssS[64 + k0 + j]), 0.f);
            afr[ks].u = pack8(f);
        }

        #pragma unroll
        for (int ct = 0; ct < 4; ++ct) {
            f32x4 acc = {0.f, 0.f, 0.f, 0.f};
            acc = __builtin_amdgcn_mfma_f32_16x16x32_bf16(afr[0].h, bfr[ct][0].h, acc, 0, 0, 0);
            acc = __builtin_amdgcn_mfma_f32_16x16x32_bf16(afr[1].h, bfr[ct][1].h, acc, 0, 0, 0);
            int col = ct * 16 + n15;
            float bcol = bias[col];
            #pragma unroll
            for (int r = 0; r < 4; ++r) {
                int rg = rowg0 + quad * 4 + r;
                float v = acc[r] + bcol;
                if (rg < NN) {
                    z2[(size_t)rg * DD + col] = f2bf_rne(v);
                    sacc[ct] += v;
                    ssacc[ct] = fmaf(v, v, ssacc[ct]);
                }
            }
        }
    }
    const int copy = blockIdx.x & (SC - 1);
    #pragma unroll
    for (int ct = 0; ct < 4; ++ct) {
        float s = sacc[ct], ss = ssacc[ct];
        s  += __shfl_xor(s, 16, 64);  s  += __shfl_xor(s, 32, 64);
        ss += __shfl_xor(ss, 16, 64); ss += __shfl_xor(ss, 32, 64);
        if (lane < 16) {
            atomicAdd(&stats2[copy * 128 + ct * 16 + lane], s);
            atomicAdd(&stats2[copy * 128 + 64 + ct * 16 + lane], ss);
        }
    }
}

// ========== K3 v2: inline BN2 + ReLU + hb write + segmented pool, 256 rows/block ==========
__global__ __launch_bounds__(256) void layer3_k(
    const unsigned short* __restrict__ z2, const float* __restrict__ stats2,
    const float* __restrict__ gamma, const float* __restrict__ beta, int off,
    const int* __restrict__ batch, unsigned short* __restrict__ hout,
    float* __restrict__ pooled, float* __restrict__ stats1z)
{
    __shared__ float ssS[128];
    int t = threadIdx.x;
    if (blockIdx.x < SC && t < 128) stats1z[blockIdx.x * 128 + t] = 0.f;
    if (t < 64) {
        float S = 0.f, SS = 0.f;
        #pragma unroll
        for (int c = 0; c < SC; ++c) { S += stats2[c * 128 + t]; SS += stats2[c * 128 + 64 + t]; }
        float inv_n = 1.0f / (float)NN;
        float mean = S * inv_n;
        float var  = SS * inv_n - mean * mean;
        float sc = gamma[off + t] * rsqrtf(var + 1e-5f);
        ssS[t] = sc;
        ssS[64 + t] = beta[off + t] - sc * mean;
    }
    __syncthreads();

    int f = t & 63;
    int q = t >> 6;
    float sc = ssS[f], sh = ssS[64 + f];
    #pragma unroll 1
    for (int ti = 0; ti < 4; ++ti) {
        int n0 = blockIdx.x * 256 + ti * 64 + q * 16;
        int nmax = NN - n0; if (nmax > 16) nmax = 16;
        float acc = 0.f;
        int curg = -1;
        #pragma unroll 4
        for (int i = 0; i < nmax; ++i) {
            int n = n0 + i;
            int g = batch[n];
            if (g != curg) {
                if (curg >= 0) atomicAdd(&pooled[(size_t)curg * DD + f], acc);
                acc = 0.f; curg = g;
            }
            float v = bf2f(z2[(size_t)n * DD + f]);
            v = fmaxf(fmaf(sc, v, sh), 0.f);
            hout[(size_t)n * DD + f] = f2bf_rne(v);
            acc += v;
        }
        if (curg >= 0) atomicAdd(&pooled[(size_t)curg * DD + f], acc);
    }
}

// ================= jumping-knowledge readout =================
__global__ void readout_k(const float* __restrict__ pooled,
                          const float* __restrict__ Wp, const float* __restrict__ bp,
                          float* __restrict__ out)
{
    int gc = blockIdx.x * blockDim.x + threadIdx.x;
    if (gc >= GG * CC) return;
    int g = gc / CC, c = gc - g * CC;
    float acc = 0.f;
    for (int l = 0; l < LL; ++l) {
        acc += bp[l * CC + c];
        const float* p  = pooled + ((size_t)l * GG + g) * DD;
        const float* wv = Wp + (size_t)l * DD * CC + c;
        #pragma unroll 8
        for (int f = 0; f < DD; ++f) acc = fmaf(p[f], wv[f * CC], acc);
    }
    out[gc] = acc;
}

extern "C" void kernel_launch(void* const* d_in, const int* in_sizes, int n_in,
                              void* d_out, int out_size, void* d_ws, size_t ws_size,
                              hipStream_t stream) {
    const float* x     = (const float*)d_in[0];
    const int*   ei    = (const int*)d_in[1];
    const int*   batch = (const int*)d_in[2];
    const float* eps   = (const float*)d_in[3];
    const float* W1    = (const float*)d_in[4];
    const float* b1    = (const float*)d_in[5];
    const float* g1    = (const float*)d_in[6];
    const float* be1   = (const float*)d_in[7];
    const float* W2    = (const float*)d_in[8];
    const float* b2    = (const float*)d_in[9];
    const float* gout  = (const float*)d_in[10];
    const float* beout = (const float*)d_in[11];
    const float* Wp    = (const float*)d_in[12];
    const float* bp    = (const float*)d_in[13];
    float* out = (float*)d_out;

    // ---- workspace layout (16B-aligned sections; bh adjacent to pooled so
    //      one memset covers bh+pooled+stats) ----
    unsigned int* stage = (unsigned int*)d_ws;          // EE*4
    int* adj   = (int*)(stage + EE);                    // EE*4
    int* offs  = adj + EE;                              // (NPAD+256)
    int* bo    = offs + NPAD + 256;                     // 400
    int* bcur  = bo + 400;                              // 400
    int* bh    = bcur + 400;                            // 400
    float* pooled = (float*)(bh + 400);                 // LL*GG*DD
    float* stats1 = pooled + (size_t)LL * GG * DD;      // SC*128
    float* stats2 = stats1 + SC * 128;                  // SC*128
    unsigned short* hb  = (unsigned short*)(stats2 + SC * 128);
    unsigned short* z1b = hb + N64;
    unsigned short* z2b = z1b + N64;
    unsigned short* wt  = z2b + N64;                    // 8*4096

    // ---- single memset: bh + pooled + stats1 + stats2 ----
    hipMemsetAsync(bh, 0, (400 + (size_t)LL * GG * DD + 2 * SC * 128) * sizeof(int), stream);
    // ---- fused prep (x->bf16 + pool0 | W^T | edge hist) ----
    prep_all_k<<<PREPG + 8 + 512, 256, 0, stream>>>(x, batch, hb, pooled, W1, W2, wt, ei, bh);
    bscan_k<<<1, 512, 0, stream>>>(bh, bo, bcur);
    partition_k<<<(EE + PCH - 1) / PCH, 256, 0, stream>>>(ei, bcur, stage);
    bucket_csr_k<<<NB, 256, 0, stream>>>(stage, bo, adj, offs);

    const int gemm_grid = (NN + 63) / 64;       // layer1: 64 rows/block
    const int big_grid  = (NN + 255) / 256;     // layer2/3: 256 rows/block
    for (int l = 0; l < LL - 1; ++l) {
        layer1_k<<<gemm_grid, 512, 0, stream>>>(
            hb, adj, offs, eps, l, wt + (size_t)l * 4096, b1 + l * DD, z1b, stats1, stats2);
        layer2_k<<<big_grid, 256, 0, stream>>>(
            z1b, stats1, g1, be1, l * DD, wt + (size_t)(4 + l) * 4096, b2 + l * DD, z2b, stats2);
        layer3_k<<<big_grid, 256, 0, stream>>>(
            z2b, stats2, gout, beout, l * DD, batch, hb,
            pooled + (size_t)(l + 1) * GG * DD, stats1);
    }
    readout_k<<<(GG * CC + 255) / 256, 256, 0, stream>>>(pooled, Wp, bp, out);
}